// Round 6
// baseline (456.621 us; speedup 1.0000x reference)
//
#include <hip/hip_runtime.h>

#define DD   64      // channels
#define KK   128     // fused GEMM K = 64 (mean) + 64 (h)
#define XSTR 132     // LDS X-tile row stride (128 + 4 pad -> breaks bank conflicts)
#define NREP 8       // histogram replicas (one per XCD residue class)

typedef unsigned int uint32;

__device__ __forceinline__ unsigned short f2bf_rne(float f) {
    uint32 u = __float_as_uint(f);
    u += 0x7fffu + ((u >> 16) & 1u);   // round-to-nearest-even
    return (unsigned short)(u >> 16);
}
__device__ __forceinline__ float bf_lo(uint32 w) { return __uint_as_float(w << 16); }
__device__ __forceinline__ float bf_hi(uint32 w) { return __uint_as_float(w & 0xffff0000u); }

// ===========================================================================
// Fused: [blocks 0..cvtBlocks) convert x -> bf16 HB (4 float4 / thread);
//        [cvtBlocks..) replicated histogram, 4 edges / thread.
// Replica = (edge>>10)&7  (1024 edges per hist block).
// ===========================================================================
__global__ __launch_bounds__(256) void hist_cvt_kernel(
    const int* __restrict__ dst, int* __restrict__ degR, int* __restrict__ rank,
    int E, const float* __restrict__ x, unsigned short* __restrict__ xb,
    int n4, int cvtBlocks, int N) {
    const int t = threadIdx.x;
    if ((int)blockIdx.x < cvtBlocks) {
        int i = blockIdx.x * 1024 + t * 4;          // float4 index
#pragma unroll
        for (int k = 0; k < 4; ++k) {
            if (i + k < n4) {
                float4 v = ((const float4*)x)[i + k];
                ushort4 p;
                p.x = f2bf_rne(v.x); p.y = f2bf_rne(v.y);
                p.z = f2bf_rne(v.z); p.w = f2bf_rne(v.w);
                ((ushort4*)xb)[i + k] = p;
            }
        }
    } else {
        int bid = blockIdx.x - cvtBlocks;
        int e = bid * 1024 + t * 4;
        if (e >= E) return;
        int* repBase = degR + (size_t)(bid & (NREP - 1)) * N;
        int4 dv = *(const int4*)(dst + e);
        int4 rk;
        rk.x = atomicAdd(&repBase[dv.x], 1);
        rk.y = atomicAdd(&repBase[dv.y], 1);
        rk.z = atomicAdd(&repBase[dv.z], 1);
        rk.w = atomicAdd(&repBase[dv.w], 1);
        *(int4*)(rank + e) = rk;
    }
}

// ===========================================================================
// scan_reduce + replica combine: per node, prefix the 8 replica counts
// (degR[r][n] <- base of replica r), total -> degI[n]; block sum -> blockSums.
// ===========================================================================
__global__ __launch_bounds__(1024) void scan_reduce(int* __restrict__ degR,
                                                    int* __restrict__ degI,
                                                    int* __restrict__ blockSums, int N) {
    __shared__ int s[1024];
    int t = threadIdx.x;
    int idx = blockIdx.x * 1024 + t;
    int tot = 0;
    if (idx < N) {
        int base = 0;
#pragma unroll
        for (int r = 0; r < NREP; ++r) {
            int c = degR[(size_t)r * N + idx];
            degR[(size_t)r * N + idx] = base;
            base += c;
        }
        tot = base;
        degI[idx] = tot;
    }
    s[t] = tot;
    __syncthreads();
    for (int d = 512; d > 0; d >>= 1) {
        if (t < d) s[t] += s[t + d];
        __syncthreads();
    }
    if (t == 0) blockSums[blockIdx.x] = s[0];
}

// ===========================================================================
// scan_final with built-in lookback: sum of preceding blockSums (nb <= 1024)
// + local Hillis-Steele scan -> exclusive offsets.
// ===========================================================================
__global__ __launch_bounds__(1024) void scan_final(const int* __restrict__ degI,
                                                   const int* __restrict__ blockSums,
                                                   int* __restrict__ offsets,
                                                   int N, int E) {
    __shared__ int s[1024];
    int t = threadIdx.x;
    int b = blockIdx.x;
    // lookback reduction over blockSums[0..b)
    s[t] = (t < b) ? blockSums[t] : 0;
    __syncthreads();
    for (int d = 512; d > 0; d >>= 1) {
        if (t < d) s[t] += s[t + d];
        __syncthreads();
    }
    int sum0 = s[0];
    __syncthreads();
    // local inclusive scan
    int idx = b * 1024 + t;
    int val = (idx < N) ? degI[idx] : 0;
    s[t] = val;
    __syncthreads();
    for (int d = 1; d < 1024; d <<= 1) {
        int v = (t >= d) ? s[t - d] : 0;
        __syncthreads();
        if (t >= d) s[t] += v;
        __syncthreads();
    }
    if (idx < N) offsets[idx] = sum0 + s[t] - val;   // exclusive
    if (b == 0 && t == 0) offsets[N] = E;
}

// ===========================================================================
// fill (atomic-free, 4 edges/thread): pos = offsets[d] + repBase[d] + rankLocal
// ===========================================================================
__global__ __launch_bounds__(256) void fill_kernel(const int* __restrict__ src,
                                                   const int* __restrict__ dst,
                                                   const int* __restrict__ offsets,
                                                   const int* __restrict__ degR,
                                                   const int* __restrict__ rank,
                                                   int* __restrict__ csr, int E, int N) {
    int e = blockIdx.x * 1024 + threadIdx.x * 4;
    if (e >= E) return;
    const int* repBase = degR + (size_t)((e >> 10) & (NREP - 1)) * N;
    int4 sv = *(const int4*)(src + e);
    int4 dv = *(const int4*)(dst + e);
    int4 rv = *(const int4*)(rank + e);
    __builtin_nontemporal_store(sv.x, &csr[offsets[dv.x] + repBase[dv.x] + rv.x]);
    __builtin_nontemporal_store(sv.y, &csr[offsets[dv.y] + repBase[dv.y] + rv.y]);
    __builtin_nontemporal_store(sv.z, &csr[offsets[dv.z] + repBase[dv.z] + rv.z]);
    __builtin_nontemporal_store(sv.w, &csr[offsets[dv.w] + repBase[dv.w] + rv.w]);
}

// ===========================================================================
// Aggregation over bf16 rows: one 8-LANE GROUP per dst node (8 nodes/wave).
// Lane q owns uint4 chunk q (16 B = 8 bf16 channels) of the 128 B row.
// Neighbors in predicated batches of 8 -> 8 gathers in flight per lane.
// ===========================================================================
__global__ __launch_bounds__(256) void aggregate_kernel(
    const unsigned short* __restrict__ hb,  // [N,64] bf16
    const int* __restrict__ offsets,        // [N+1]
    const int* __restrict__ csr,            // [E]
    float* __restrict__ agg,                // [N,64] <- mean (fp32)
    int N) {
    int node = (blockIdx.x * 256 + threadIdx.x) >> 3;
    if (node >= N) return;
    const int q = threadIdx.x & 7;          // 16 B chunk within row

    const int off0 = offsets[node];
    const int off1 = offsets[node + 1];

    float a0 = 0.f, a1 = 0.f, a2 = 0.f, a3 = 0.f,
          a4 = 0.f, a5 = 0.f, a6 = 0.f, a7 = 0.f;

    for (int j = off0; j < off1; j += 8) {
        uint4 v[8];
#pragma unroll
        for (int s = 0; s < 8; ++s) {
            uint4 t = make_uint4(0u, 0u, 0u, 0u);
            int idx = j + s;
            if (idx < off1) {
                int sn = __builtin_nontemporal_load(&csr[idx]);
                t = ((const uint4*)(hb + (size_t)sn * DD))[q];
            }
            v[s] = t;
        }
#pragma unroll
        for (int s = 0; s < 8; ++s) {
            a0 += bf_lo(v[s].x); a1 += bf_hi(v[s].x);
            a2 += bf_lo(v[s].y); a3 += bf_hi(v[s].y);
            a4 += bf_lo(v[s].z); a5 += bf_hi(v[s].z);
            a6 += bf_lo(v[s].w); a7 += bf_hi(v[s].w);
        }
    }
    float invd = 1.0f / fmaxf((float)(off1 - off0), 1.0f);
    float4 lo = make_float4(a0 * invd, a1 * invd, a2 * invd, a3 * invd);
    float4 hi = make_float4(a4 * invd, a5 * invd, a6 * invd, a7 * invd);
    *(float4*)(&agg[(size_t)node * DD + q * 8])     = lo;
    *(float4*)(&agg[(size_t)node * DD + q * 8 + 4]) = hi;
}

// ===========================================================================
// Fused per-node update: out = [mean || h] @ [Wl ; Wr] + bl
//   MODE 0: h' = relu(LN(out)) + h   (also writes bf16 shadow outb)
//   MODE 1: h' = l2normalize(out + h)
// ===========================================================================
template <int MODE>
__global__ __launch_bounds__(256) void node_update(
    const float* __restrict__ h,    // [N,64] layer input (residual source)
    const float* __restrict__ mean, // [N,64] precomputed neighbor mean
    const float* __restrict__ Wl,   // [64,64] row-major
    const float* __restrict__ bl,   // [64]
    const float* __restrict__ Wr,   // [64,64]
    const float* __restrict__ g,    // [64] LN gamma (MODE 0)
    const float* __restrict__ b,    // [64] LN beta  (MODE 0)
    float* __restrict__ out,        // [N,64]
    unsigned short* __restrict__ outb, // [N,64] bf16 shadow (MODE 0)
    int nNodes) {
    __shared__ float sW[KK * DD];      // rows 0..63 = Wl, 64..127 = Wr  ([k][c])
    __shared__ float sX[64 * XSTR];    // [n][k]; k<64: mean row, k>=64: h row
    __shared__ float sbl[DD], sg[DD], sb[DD];

    const int t = threadIdx.x;

    for (int i = t; i < DD * DD; i += 256) {
        sW[i]           = Wl[i];
        sW[DD * DD + i] = Wr[i];
    }
    if (t < DD) {
        sbl[t] = bl[t];
        if (MODE == 0) { sg[t] = g[t]; sb[t] = b[t]; }
    }

    const int nbase = blockIdx.x * 64;

    for (int r = 0; r < 8; ++r) {
        int idx  = r * 256 + t;
        int node = idx >> 5;       // 0..63
        int q    = idx & 31;       // float4 within the 128-float row
        int n    = nbase + node;
        float4 v = make_float4(0.f, 0.f, 0.f, 0.f);
        if (n < nNodes) {
            v = (q < 16) ? ((const float4*)(mean + (size_t)n * DD))[q]
                         : ((const float4*)(h    + (size_t)n * DD))[q - 16];
        }
        *(float4*)(&sX[node * XSTR + q * 4]) = v;
    }
    __syncthreads();

    const int c0 = (t & 15) * 4;   // output cols c0..c0+3
    const int n0 = (t >> 4) * 4;   // nodes n0..n0+3 (within tile)

    float acc[4][4];
#pragma unroll
    for (int i = 0; i < 4; ++i)
#pragma unroll
        for (int j = 0; j < 4; ++j) acc[i][j] = sbl[c0 + j];

#pragma unroll 8
    for (int k = 0; k < KK; ++k) {
        const float4 w = *(const float4*)(&sW[k * DD + c0]);
#pragma unroll
        for (int i = 0; i < 4; ++i) {
            float xv = sX[(n0 + i) * XSTR + k];
            acc[i][0] = fmaf(xv, w.x, acc[i][0]);
            acc[i][1] = fmaf(xv, w.y, acc[i][1]);
            acc[i][2] = fmaf(xv, w.z, acc[i][2]);
            acc[i][3] = fmaf(xv, w.w, acc[i][3]);
        }
    }

    float res[4][4];
#pragma unroll
    for (int i = 0; i < 4; ++i) {
        float4 rv = *(const float4*)(&sX[(n0 + i) * XSTR + 64 + c0]);
        res[i][0] = rv.x; res[i][1] = rv.y; res[i][2] = rv.z; res[i][3] = rv.w;
    }

#pragma unroll
    for (int i = 0; i < 4; ++i) {
        int nn = nbase + n0 + i;
        float4 o;
        if (MODE == 0) {
            float s = acc[i][0] + acc[i][1] + acc[i][2] + acc[i][3];
            s += __shfl_xor(s, 1, 64);
            s += __shfl_xor(s, 2, 64);
            s += __shfl_xor(s, 4, 64);
            s += __shfl_xor(s, 8, 64);
            float mu = s * (1.0f / 64.0f);
            float d0 = acc[i][0] - mu, d1 = acc[i][1] - mu,
                  d2 = acc[i][2] - mu, d3 = acc[i][3] - mu;
            float qq = d0 * d0 + d1 * d1 + d2 * d2 + d3 * d3;
            qq += __shfl_xor(qq, 1, 64);
            qq += __shfl_xor(qq, 2, 64);
            qq += __shfl_xor(qq, 4, 64);
            qq += __shfl_xor(qq, 8, 64);
            float rstd = rsqrtf(qq * (1.0f / 64.0f) + 1e-5f);
            o.x = fmaxf(d0 * rstd * sg[c0 + 0] + sb[c0 + 0], 0.f) + res[i][0];
            o.y = fmaxf(d1 * rstd * sg[c0 + 1] + sb[c0 + 1], 0.f) + res[i][1];
            o.z = fmaxf(d2 * rstd * sg[c0 + 2] + sb[c0 + 2], 0.f) + res[i][2];
            o.w = fmaxf(d3 * rstd * sg[c0 + 3] + sb[c0 + 3], 0.f) + res[i][3];
        } else {
            float y0 = acc[i][0] + res[i][0], y1 = acc[i][1] + res[i][1],
                  y2 = acc[i][2] + res[i][2], y3 = acc[i][3] + res[i][3];
            float qq = y0 * y0 + y1 * y1 + y2 * y2 + y3 * y3;
            qq += __shfl_xor(qq, 1, 64);
            qq += __shfl_xor(qq, 2, 64);
            qq += __shfl_xor(qq, 4, 64);
            qq += __shfl_xor(qq, 8, 64);
            float inv = 1.0f / fmaxf(sqrtf(qq), 1e-12f);
            o.x = y0 * inv; o.y = y1 * inv; o.z = y2 * inv; o.w = y3 * inv;
        }
        if (nn < nNodes) {
            *(float4*)(&out[(size_t)nn * DD + c0]) = o;
            if (MODE == 0) {
                ushort4 p;
                p.x = f2bf_rne(o.x); p.y = f2bf_rne(o.y);
                p.z = f2bf_rne(o.z); p.w = f2bf_rne(o.w);
                *(ushort4*)(&outb[(size_t)nn * DD + c0]) = p;
            }
        }
    }
}

// ===========================================================================
extern "C" void kernel_launch(void* const* d_in, const int* in_sizes, int n_in,
                              void* d_out, int out_size, void* d_ws, size_t ws_size,
                              hipStream_t stream) {
    const float* x   = (const float*)d_in[0];
    const int*   ei  = (const int*)d_in[1];   // [2, E] int32: row0 = src, row1 = dst
    const float* Wl0 = (const float*)d_in[2];
    const float* bl0 = (const float*)d_in[3];
    const float* Wr0 = (const float*)d_in[4];
    const float* Wl1 = (const float*)d_in[5];
    const float* bl1 = (const float*)d_in[6];
    const float* Wr1 = (const float*)d_in[7];
    const float* Wl2 = (const float*)d_in[8];
    const float* bl2 = (const float*)d_in[9];
    const float* Wr2 = (const float*)d_in[10];
    const float* g0  = (const float*)d_in[11];
    const float* b0  = (const float*)d_in[12];
    const float* g1  = (const float*)d_in[13];
    const float* b1  = (const float*)d_in[14];

    const int N = in_sizes[0] / DD;   // 100000
    const int E = in_sizes[1] / 2;    // 1250000
    const int* src = ei;
    const int* dst = ei + E;

    // Workspace: A | B | AGG (f32, N*64 each) | HB (bf16) | degI[N] |
    //            offsets[N+1] | bsums[1024] | csr[E]
    // Aliases: degR[8N] -> A (dead before nu0 writes A);
    //          rank[E]  -> AGG (dead before agg0 writes AGG).
    float* A       = (float*)d_ws;
    float* B       = A + (size_t)N * DD;
    float* AGG     = B + (size_t)N * DD;
    int*   degR    = (int*)A;
    int*   rank    = (int*)AGG;
    unsigned short* HB = (unsigned short*)(AGG + (size_t)N * DD);
    int*   degI    = (int*)(HB + (size_t)N * DD);
    int*   offsets = degI + N;
    int*   bsums   = offsets + (N + 1);
    int*   csr     = bsums + 1024;
    float* out     = (float*)d_out;

    const int tiles = (N + 63) / 64;
    const int nb    = (N + 1023) / 1024;
    const int agrid = (N + 31) / 32;          // 32 nodes/block (8-lane groups)
    const int n4        = N * DD / 4;         // float4 count for cvt
    const int cvtBlocks = (n4 + 1023) / 1024;
    const int histBlocks = (E + 1023) / 1024;
    const int fgrid      = (E + 1023) / 1024;

    // ---- CSR build (replicated histogram; graph static across layers)
    hipMemsetAsync(degR, 0, (size_t)NREP * N * sizeof(int), stream);
    hist_cvt_kernel<<<cvtBlocks + histBlocks, 256, 0, stream>>>(
        dst, degR, rank, E, x, HB, n4, cvtBlocks, N);
    scan_reduce<<<nb, 1024, 0, stream>>>(degR, degI, bsums, N);
    scan_final<<<nb, 1024, 0, stream>>>(degI, bsums, offsets, N, E);
    fill_kernel<<<fgrid, 256, 0, stream>>>(src, dst, offsets, degR, rank, csr, E, N);

    // ---- layer 0 (x -> A); HB = bf16(x) already built by hist_cvt
    aggregate_kernel<<<agrid, 256, 0, stream>>>(HB, offsets, csr, AGG, N);
    node_update<0><<<tiles, 256, 0, stream>>>(x, AGG, Wl0, bl0, Wr0, g0, b0, A, HB, N);

    // ---- layer 1 (A -> B); HB now bf16(A)
    aggregate_kernel<<<agrid, 256, 0, stream>>>(HB, offsets, csr, AGG, N);
    node_update<0><<<tiles, 256, 0, stream>>>(A, AGG, Wl1, bl1, Wr1, g1, b1, B, HB, N);

    // ---- layer 2 (B -> out); HB now bf16(B)
    aggregate_kernel<<<agrid, 256, 0, stream>>>(HB, offsets, csr, AGG, N);
    node_update<1><<<tiles, 256, 0, stream>>>(B, AGG, Wl2, bl2, Wr2, nullptr, nullptr, out, nullptr, N);
}

// Round 7
// 373.802 us; speedup vs baseline: 1.2216x; 1.2216x over previous
//
#include <hip/hip_runtime.h>

#define DD   64      // channels
#define KK   128     // fused GEMM K = 64 (mean) + 64 (h)
#define XSTR 132     // LDS X-tile row stride (128 + 4 pad -> breaks bank conflicts)
#define BSH  9       // 512 nodes per bucket
#define BNODES 512
#define BCAPSH 13    // 8192 edges capacity per bucket (mean 6378 + 22 sigma)

typedef unsigned int uint32;

__device__ __forceinline__ unsigned short f2bf_rne(float f) {
    uint32 u = __float_as_uint(f);
    u += 0x7fffu + ((u >> 16) & 1u);   // round-to-nearest-even
    return (unsigned short)(u >> 16);
}
__device__ __forceinline__ float bf_lo(uint32 w) { return __uint_as_float(w << 16); }
__device__ __forceinline__ float bf_hi(uint32 w) { return __uint_as_float(w & 0xffff0000u); }

// ===========================================================================
// x (fp32) -> bf16 shadow; block 0 also zeroes the bucket counters.
// ===========================================================================
__global__ __launch_bounds__(256) void cvt_kernel(const float* __restrict__ x,
                                                  unsigned short* __restrict__ xb,
                                                  int n4, int* __restrict__ gCnt) {
    if (blockIdx.x == 0 && threadIdx.x < 256) gCnt[threadIdx.x] = 0;
    int i = blockIdx.x * 256 + threadIdx.x;
    if (i < n4) {
        float4 v = ((const float4*)x)[i];
        ushort4 p;
        p.x = f2bf_rne(v.x); p.y = f2bf_rne(v.y);
        p.z = f2bf_rne(v.z); p.w = f2bf_rne(v.w);
        ((ushort4*)xb)[i] = p;
    }
}

// ===========================================================================
// Pass 1: bucket edges by dst>>9. Block = 1024 thr, 4096 edges.
// LDS histogram -> one global atomicAdd per (block,bucket) -> scatter
// (src,dst) int2 into fixed-capacity bucket regions.
// ===========================================================================
__global__ __launch_bounds__(1024) void bucket_kernel(const int* __restrict__ src,
                                                      const int* __restrict__ dst,
                                                      int* __restrict__ gCnt,
                                                      int2* __restrict__ buf, int E) {
    __shared__ int ldsCnt[256];
    __shared__ int base[256];
    const int t = threadIdx.x;
    if (t < 256) ldsCnt[t] = 0;
    __syncthreads();

    const int e0 = blockIdx.x * 4096;
    int bk[4], rk[4], sv[4], dv[4];
#pragma unroll
    for (int k = 0; k < 4; ++k) {
        int e = e0 + k * 1024 + t;
        bk[k] = -1;
        if (e < E) {
            dv[k] = dst[e];
            sv[k] = src[e];
            bk[k] = dv[k] >> BSH;
            rk[k] = atomicAdd(&ldsCnt[bk[k]], 1);
        }
    }
    __syncthreads();
    if (t < 256 && ldsCnt[t] > 0) base[t] = atomicAdd(&gCnt[t], ldsCnt[t]);
    __syncthreads();
#pragma unroll
    for (int k = 0; k < 4; ++k) {
        if (bk[k] >= 0) {
            int pos = (bk[k] << BCAPSH) + base[bk[k]] + rk[k];
            buf[pos] = make_int2(sv[k], dv[k]);
        }
    }
}

// ===========================================================================
// Exclusive scan over bucket counts (NB <= 256), one block.
// ===========================================================================
__global__ __launch_bounds__(256) void scan_buckets(const int* __restrict__ gCnt,
                                                    int* __restrict__ csrBase, int NB) {
    __shared__ int s[256];
    int t = threadIdx.x;
    int v = (t < NB) ? gCnt[t] : 0;
    s[t] = v;
    __syncthreads();
    for (int d = 1; d < 256; d <<= 1) {
        int u = (t >= d) ? s[t - d] : 0;
        __syncthreads();
        if (t >= d) s[t] += u;
        __syncthreads();
    }
    if (t < NB) csrBase[t] = s[t] - v;   // exclusive
}

// ===========================================================================
// Pass 2: one block per bucket. LDS count -> LDS scan -> offsets (coalesced)
// -> scatter src into this bucket's csr window (single-CU stores, no bounce).
// ===========================================================================
__global__ __launch_bounds__(512) void csr_build(const int2* __restrict__ buf,
                                                 const int* __restrict__ gCnt,
                                                 const int* __restrict__ csrBase,
                                                 int* __restrict__ offsets,
                                                 int* __restrict__ csr, int N, int E) {
    __shared__ int c1[BNODES];
    __shared__ int s[BNODES];
    const int b = blockIdx.x;
    const int t = threadIdx.x;
    c1[t] = 0;
    __syncthreads();

    const int cnt = gCnt[b];
    const int2* bb = buf + ((size_t)b << BCAPSH);
    for (int i = t; i < cnt; i += 512) atomicAdd(&c1[bb[i].y & (BNODES - 1)], 1);
    __syncthreads();

    int v = c1[t];
    s[t] = v;
    __syncthreads();
    for (int d = 1; d < BNODES; d <<= 1) {
        int u = (t >= d) ? s[t - d] : 0;
        __syncthreads();
        if (t >= d) s[t] += u;
        __syncthreads();
    }
    int excl = s[t] - v;
    const int base = csrBase[b];
    const int node = (b << BSH) + t;
    if (node < N) offsets[node] = base + excl;
    if (b == 0 && t == 0) offsets[N] = E;
    __syncthreads();
    s[t] = excl;
    c1[t] = 0;
    __syncthreads();

    for (int i = t; i < cnt; i += 512) {
        int2 e = bb[i];
        int d = e.y & (BNODES - 1);
        int r = atomicAdd(&c1[d], 1);
        csr[base + s[d] + r] = e.x;
    }
}

// ===========================================================================
// Aggregation over bf16 rows: one 8-LANE GROUP per dst node (8 nodes/wave).
// ===========================================================================
__global__ __launch_bounds__(256) void aggregate_kernel(
    const unsigned short* __restrict__ hb,  // [N,64] bf16
    const int* __restrict__ offsets,        // [N+1]
    const int* __restrict__ csr,            // [E]
    float* __restrict__ agg,                // [N,64] <- mean (fp32)
    int N) {
    int node = (blockIdx.x * 256 + threadIdx.x) >> 3;
    if (node >= N) return;
    const int q = threadIdx.x & 7;          // 16 B chunk within row

    const int off0 = offsets[node];
    const int off1 = offsets[node + 1];

    float a0 = 0.f, a1 = 0.f, a2 = 0.f, a3 = 0.f,
          a4 = 0.f, a5 = 0.f, a6 = 0.f, a7 = 0.f;

    for (int j = off0; j < off1; j += 8) {
        uint4 v[8];
#pragma unroll
        for (int s = 0; s < 8; ++s) {
            uint4 t = make_uint4(0u, 0u, 0u, 0u);
            int idx = j + s;
            if (idx < off1) {
                int sn = __builtin_nontemporal_load(&csr[idx]);
                t = ((const uint4*)(hb + (size_t)sn * DD))[q];
            }
            v[s] = t;
        }
#pragma unroll
        for (int s = 0; s < 8; ++s) {
            a0 += bf_lo(v[s].x); a1 += bf_hi(v[s].x);
            a2 += bf_lo(v[s].y); a3 += bf_hi(v[s].y);
            a4 += bf_lo(v[s].z); a5 += bf_hi(v[s].z);
            a6 += bf_lo(v[s].w); a7 += bf_hi(v[s].w);
        }
    }
    float invd = 1.0f / fmaxf((float)(off1 - off0), 1.0f);
    float4 lo = make_float4(a0 * invd, a1 * invd, a2 * invd, a3 * invd);
    float4 hi = make_float4(a4 * invd, a5 * invd, a6 * invd, a7 * invd);
    *(float4*)(&agg[(size_t)node * DD + q * 8])     = lo;
    *(float4*)(&agg[(size_t)node * DD + q * 8 + 4]) = hi;
}

// ===========================================================================
// Fused per-node update: out = [mean || h] @ [Wl ; Wr] + bl
//   MODE 0: h' = relu(LN(out)) + h   (also writes bf16 shadow outb)
//   MODE 1: h' = l2normalize(out + h)
// ===========================================================================
template <int MODE>
__global__ __launch_bounds__(256) void node_update(
    const float* __restrict__ h,    // [N,64] layer input (residual source)
    const float* __restrict__ mean, // [N,64] precomputed neighbor mean
    const float* __restrict__ Wl,   // [64,64] row-major
    const float* __restrict__ bl,   // [64]
    const float* __restrict__ Wr,   // [64,64]
    const float* __restrict__ g,    // [64] LN gamma (MODE 0)
    const float* __restrict__ b,    // [64] LN beta  (MODE 0)
    float* __restrict__ out,        // [N,64]
    unsigned short* __restrict__ outb, // [N,64] bf16 shadow (MODE 0)
    int nNodes) {
    __shared__ float sW[KK * DD];      // rows 0..63 = Wl, 64..127 = Wr  ([k][c])
    __shared__ float sX[64 * XSTR];    // [n][k]; k<64: mean row, k>=64: h row
    __shared__ float sbl[DD], sg[DD], sb[DD];

    const int t = threadIdx.x;

    for (int i = t; i < DD * DD; i += 256) {
        sW[i]           = Wl[i];
        sW[DD * DD + i] = Wr[i];
    }
    if (t < DD) {
        sbl[t] = bl[t];
        if (MODE == 0) { sg[t] = g[t]; sb[t] = b[t]; }
    }

    const int nbase = blockIdx.x * 64;

    for (int r = 0; r < 8; ++r) {
        int idx  = r * 256 + t;
        int node = idx >> 5;       // 0..63
        int q    = idx & 31;       // float4 within the 128-float row
        int n    = nbase + node;
        float4 v = make_float4(0.f, 0.f, 0.f, 0.f);
        if (n < nNodes) {
            v = (q < 16) ? ((const float4*)(mean + (size_t)n * DD))[q]
                         : ((const float4*)(h    + (size_t)n * DD))[q - 16];
        }
        *(float4*)(&sX[node * XSTR + q * 4]) = v;
    }
    __syncthreads();

    const int c0 = (t & 15) * 4;   // output cols c0..c0+3
    const int n0 = (t >> 4) * 4;   // nodes n0..n0+3 (within tile)

    float acc[4][4];
#pragma unroll
    for (int i = 0; i < 4; ++i)
#pragma unroll
        for (int j = 0; j < 4; ++j) acc[i][j] = sbl[c0 + j];

#pragma unroll 8
    for (int k = 0; k < KK; ++k) {
        const float4 w = *(const float4*)(&sW[k * DD + c0]);
#pragma unroll
        for (int i = 0; i < 4; ++i) {
            float xv = sX[(n0 + i) * XSTR + k];
            acc[i][0] = fmaf(xv, w.x, acc[i][0]);
            acc[i][1] = fmaf(xv, w.y, acc[i][1]);
            acc[i][2] = fmaf(xv, w.z, acc[i][2]);
            acc[i][3] = fmaf(xv, w.w, acc[i][3]);
        }
    }

    float res[4][4];
#pragma unroll
    for (int i = 0; i < 4; ++i) {
        float4 rv = *(const float4*)(&sX[(n0 + i) * XSTR + 64 + c0]);
        res[i][0] = rv.x; res[i][1] = rv.y; res[i][2] = rv.z; res[i][3] = rv.w;
    }

#pragma unroll
    for (int i = 0; i < 4; ++i) {
        int nn = nbase + n0 + i;
        float4 o;
        if (MODE == 0) {
            float s = acc[i][0] + acc[i][1] + acc[i][2] + acc[i][3];
            s += __shfl_xor(s, 1, 64);
            s += __shfl_xor(s, 2, 64);
            s += __shfl_xor(s, 4, 64);
            s += __shfl_xor(s, 8, 64);
            float mu = s * (1.0f / 64.0f);
            float d0 = acc[i][0] - mu, d1 = acc[i][1] - mu,
                  d2 = acc[i][2] - mu, d3 = acc[i][3] - mu;
            float qq = d0 * d0 + d1 * d1 + d2 * d2 + d3 * d3;
            qq += __shfl_xor(qq, 1, 64);
            qq += __shfl_xor(qq, 2, 64);
            qq += __shfl_xor(qq, 4, 64);
            qq += __shfl_xor(qq, 8, 64);
            float rstd = rsqrtf(qq * (1.0f / 64.0f) + 1e-5f);
            o.x = fmaxf(d0 * rstd * sg[c0 + 0] + sb[c0 + 0], 0.f) + res[i][0];
            o.y = fmaxf(d1 * rstd * sg[c0 + 1] + sb[c0 + 1], 0.f) + res[i][1];
            o.z = fmaxf(d2 * rstd * sg[c0 + 2] + sb[c0 + 2], 0.f) + res[i][2];
            o.w = fmaxf(d3 * rstd * sg[c0 + 3] + sb[c0 + 3], 0.f) + res[i][3];
        } else {
            float y0 = acc[i][0] + res[i][0], y1 = acc[i][1] + res[i][1],
                  y2 = acc[i][2] + res[i][2], y3 = acc[i][3] + res[i][3];
            float qq = y0 * y0 + y1 * y1 + y2 * y2 + y3 * y3;
            qq += __shfl_xor(qq, 1, 64);
            qq += __shfl_xor(qq, 2, 64);
            qq += __shfl_xor(qq, 4, 64);
            qq += __shfl_xor(qq, 8, 64);
            float inv = 1.0f / fmaxf(sqrtf(qq), 1e-12f);
            o.x = y0 * inv; o.y = y1 * inv; o.z = y2 * inv; o.w = y3 * inv;
        }
        if (nn < nNodes) {
            *(float4*)(&out[(size_t)nn * DD + c0]) = o;
            if (MODE == 0) {
                ushort4 p;
                p.x = f2bf_rne(o.x); p.y = f2bf_rne(o.y);
                p.z = f2bf_rne(o.z); p.w = f2bf_rne(o.w);
                *(ushort4*)(&outb[(size_t)nn * DD + c0]) = p;
            }
        }
    }
}

// ===========================================================================
extern "C" void kernel_launch(void* const* d_in, const int* in_sizes, int n_in,
                              void* d_out, int out_size, void* d_ws, size_t ws_size,
                              hipStream_t stream) {
    const float* x   = (const float*)d_in[0];
    const int*   ei  = (const int*)d_in[1];   // [2, E] int32: row0 = src, row1 = dst
    const float* Wl0 = (const float*)d_in[2];
    const float* bl0 = (const float*)d_in[3];
    const float* Wr0 = (const float*)d_in[4];
    const float* Wl1 = (const float*)d_in[5];
    const float* bl1 = (const float*)d_in[6];
    const float* Wr1 = (const float*)d_in[7];
    const float* Wl2 = (const float*)d_in[8];
    const float* bl2 = (const float*)d_in[9];
    const float* Wr2 = (const float*)d_in[10];
    const float* g0  = (const float*)d_in[11];
    const float* b0  = (const float*)d_in[12];
    const float* g1  = (const float*)d_in[13];
    const float* b1  = (const float*)d_in[14];

    const int N = in_sizes[0] / DD;   // 100000
    const int E = in_sizes[1] / 2;    // 1250000
    const int* src = ei;
    const int* dst = ei + E;
    const int NB = (N + BNODES - 1) >> BSH;   // 196 buckets

    // Workspace: A | B | AGG (f32, N*64 each) | HB (bf16) | offsets[N+1] |
    //            gCnt[256] | csrBase[256] | csr[E]
    // bucketBuf int2[NB<<13] aliases A (dead before nu0 writes A).
    float* A       = (float*)d_ws;
    float* B       = A + (size_t)N * DD;
    float* AGG     = B + (size_t)N * DD;
    int2*  bucketBuf = (int2*)A;
    unsigned short* HB = (unsigned short*)(AGG + (size_t)N * DD);
    int*   offsets = (int*)(HB + (size_t)N * DD);
    int*   gCnt    = offsets + (N + 1);
    int*   csrBase = gCnt + 256;
    int*   csr     = csrBase + 256;
    float* out     = (float*)d_out;

    const int tiles = (N + 63) / 64;
    const int agrid = (N + 31) / 32;          // 32 nodes/block (8-lane groups)
    const int n4    = N * DD / 4;             // float4 count for cvt
    const int cgrid = (n4 + 255) / 256;
    const int bgrid = (E + 4095) / 4096;

    // ---- CSR build: bucket counting sort (graph static across layers)
    cvt_kernel<<<cgrid, 256, 0, stream>>>(x, HB, n4, gCnt);   // HB=bf16(x), gCnt=0
    bucket_kernel<<<bgrid, 1024, 0, stream>>>(src, dst, gCnt, bucketBuf, E);
    scan_buckets<<<1, 256, 0, stream>>>(gCnt, csrBase, NB);
    csr_build<<<NB, 512, 0, stream>>>(bucketBuf, gCnt, csrBase, offsets, csr, N, E);

    // ---- layer 0 (x -> A)
    aggregate_kernel<<<agrid, 256, 0, stream>>>(HB, offsets, csr, AGG, N);
    node_update<0><<<tiles, 256, 0, stream>>>(x, AGG, Wl0, bl0, Wr0, g0, b0, A, HB, N);

    // ---- layer 1 (A -> B); HB now bf16(A)
    aggregate_kernel<<<agrid, 256, 0, stream>>>(HB, offsets, csr, AGG, N);
    node_update<0><<<tiles, 256, 0, stream>>>(A, AGG, Wl1, bl1, Wr1, g1, b1, B, HB, N);

    // ---- layer 2 (B -> out); HB now bf16(B)
    aggregate_kernel<<<agrid, 256, 0, stream>>>(HB, offsets, csr, AGG, N);
    node_update<1><<<tiles, 256, 0, stream>>>(B, AGG, Wl2, bl2, Wr2, nullptr, nullptr, out, nullptr, N);
}

// Round 8
// 314.205 us; speedup vs baseline: 1.4533x; 1.1897x over previous
//
#include <hip/hip_runtime.h>

#define DD   64      // channels
#define WSTR 136     // LDS W^T row stride in bf16 elems (128 + 8 -> 2-way conflicts only)
#define BSH  9       // 512 nodes per bucket
#define BNODES 512
#define BCAPSH 13    // 8192 edges capacity per bucket

typedef unsigned int uint32;
typedef __attribute__((ext_vector_type(8))) short short8;   // 8 bf16 (4 VGPRs)
typedef __attribute__((ext_vector_type(4))) float f32x4;    // MFMA accumulator

__device__ __forceinline__ unsigned short f2bf_rne(float f) {
    uint32 u = __float_as_uint(f);
    u += 0x7fffu + ((u >> 16) & 1u);   // round-to-nearest-even
    return (unsigned short)(u >> 16);
}
__device__ __forceinline__ float bf_lo(uint32 w) { return __uint_as_float(w << 16); }
__device__ __forceinline__ float bf_hi(uint32 w) { return __uint_as_float(w & 0xffff0000u); }

// ===========================================================================
// x (fp32) -> bf16 shadow; block 0 also zeroes the bucket counters.
// ===========================================================================
__global__ __launch_bounds__(256) void cvt_kernel(const float* __restrict__ x,
                                                  unsigned short* __restrict__ xb,
                                                  int n4, int* __restrict__ gCnt) {
    if (blockIdx.x == 0 && threadIdx.x < 256) gCnt[threadIdx.x] = 0;
    int i = blockIdx.x * 256 + threadIdx.x;
    if (i < n4) {
        float4 v = ((const float4*)x)[i];
        ushort4 p;
        p.x = f2bf_rne(v.x); p.y = f2bf_rne(v.y);
        p.z = f2bf_rne(v.z); p.w = f2bf_rne(v.w);
        ((ushort4*)xb)[i] = p;
    }
}

// ===========================================================================
// Pass 1: bucket edges by dst>>9 (LDS histogram, one global atomic per
// (block,bucket), scatter (src,dst) into fixed-capacity bucket regions).
// ===========================================================================
__global__ __launch_bounds__(1024) void bucket_kernel(const int* __restrict__ src,
                                                      const int* __restrict__ dst,
                                                      int* __restrict__ gCnt,
                                                      int2* __restrict__ buf, int E) {
    __shared__ int ldsCnt[256];
    __shared__ int base[256];
    const int t = threadIdx.x;
    if (t < 256) ldsCnt[t] = 0;
    __syncthreads();

    const int e0 = blockIdx.x * 4096;
    int bk[4], rk[4], sv[4], dv[4];
#pragma unroll
    for (int k = 0; k < 4; ++k) {
        int e = e0 + k * 1024 + t;
        bk[k] = -1;
        if (e < E) {
            dv[k] = dst[e];
            sv[k] = src[e];
            bk[k] = dv[k] >> BSH;
            rk[k] = atomicAdd(&ldsCnt[bk[k]], 1);
        }
    }
    __syncthreads();
    if (t < 256 && ldsCnt[t] > 0) base[t] = atomicAdd(&gCnt[t], ldsCnt[t]);
    __syncthreads();
#pragma unroll
    for (int k = 0; k < 4; ++k) {
        if (bk[k] >= 0) {
            int pos = (bk[k] << BCAPSH) + base[bk[k]] + rk[k];
            buf[pos] = make_int2(sv[k], dv[k]);
        }
    }
}

// ===========================================================================
// Exclusive scan over bucket counts (NB <= 256), one block.
// ===========================================================================
__global__ __launch_bounds__(256) void scan_buckets(const int* __restrict__ gCnt,
                                                    int* __restrict__ csrBase, int NB) {
    __shared__ int s[256];
    int t = threadIdx.x;
    int v = (t < NB) ? gCnt[t] : 0;
    s[t] = v;
    __syncthreads();
    for (int d = 1; d < 256; d <<= 1) {
        int u = (t >= d) ? s[t - d] : 0;
        __syncthreads();
        if (t >= d) s[t] += u;
        __syncthreads();
    }
    if (t < NB) csrBase[t] = s[t] - v;   // exclusive
}

// ===========================================================================
// Pass 2: one block per bucket -> offsets + csr (single-CU stores).
// ===========================================================================
__global__ __launch_bounds__(512) void csr_build(const int2* __restrict__ buf,
                                                 const int* __restrict__ gCnt,
                                                 const int* __restrict__ csrBase,
                                                 int* __restrict__ offsets,
                                                 int* __restrict__ csr, int N, int E) {
    __shared__ int c1[BNODES];
    __shared__ int s[BNODES];
    const int b = blockIdx.x;
    const int t = threadIdx.x;
    c1[t] = 0;
    __syncthreads();

    const int cnt = gCnt[b];
    const int2* bb = buf + ((size_t)b << BCAPSH);
    for (int i = t; i < cnt; i += 512) atomicAdd(&c1[bb[i].y & (BNODES - 1)], 1);
    __syncthreads();

    int v = c1[t];
    s[t] = v;
    __syncthreads();
    for (int d = 1; d < BNODES; d <<= 1) {
        int u = (t >= d) ? s[t - d] : 0;
        __syncthreads();
        if (t >= d) s[t] += u;
        __syncthreads();
    }
    int excl = s[t] - v;
    const int base = csrBase[b];
    const int node = (b << BSH) + t;
    if (node < N) offsets[node] = base + excl;
    if (b == 0 && t == 0) offsets[N] = E;
    __syncthreads();
    s[t] = excl;
    c1[t] = 0;
    __syncthreads();

    for (int i = t; i < cnt; i += 512) {
        int2 e = bb[i];
        int d = e.y & (BNODES - 1);
        int r = atomicAdd(&c1[d], 1);
        csr[base + s[d] + r] = e.x;
    }
}

// ===========================================================================
// Aggregation over bf16 rows: one 8-LANE GROUP per dst node. Writes the
// MEAN row in bf16 (16 B per lane) -> feeds the MFMA A-operand directly.
// ===========================================================================
__global__ __launch_bounds__(256) void aggregate_kernel(
    const unsigned short* __restrict__ hb,  // [N,64] bf16
    const int* __restrict__ offsets,        // [N+1]
    const int* __restrict__ csr,            // [E]
    unsigned short* __restrict__ aggb,      // [N,64] bf16 <- mean
    int N) {
    int node = (blockIdx.x * 256 + threadIdx.x) >> 3;
    if (node >= N) return;
    const int q = threadIdx.x & 7;          // 16 B chunk within row

    const int off0 = offsets[node];
    const int off1 = offsets[node + 1];

    float a0 = 0.f, a1 = 0.f, a2 = 0.f, a3 = 0.f,
          a4 = 0.f, a5 = 0.f, a6 = 0.f, a7 = 0.f;

    for (int j = off0; j < off1; j += 8) {
        uint4 v[8];
#pragma unroll
        for (int s = 0; s < 8; ++s) {
            uint4 t = make_uint4(0u, 0u, 0u, 0u);
            int idx = j + s;
            if (idx < off1) {
                int sn = __builtin_nontemporal_load(&csr[idx]);
                t = ((const uint4*)(hb + (size_t)sn * DD))[q];
            }
            v[s] = t;
        }
#pragma unroll
        for (int s = 0; s < 8; ++s) {
            a0 += bf_lo(v[s].x); a1 += bf_hi(v[s].x);
            a2 += bf_lo(v[s].y); a3 += bf_hi(v[s].y);
            a4 += bf_lo(v[s].z); a5 += bf_hi(v[s].z);
            a6 += bf_lo(v[s].w); a7 += bf_hi(v[s].w);
        }
    }
    float invd = 1.0f / fmaxf((float)(off1 - off0), 1.0f);
    unsigned short* orow = aggb + (size_t)node * DD + q * 8;
    ushort4 pa, pb;
    pa.x = f2bf_rne(a0 * invd); pa.y = f2bf_rne(a1 * invd);
    pa.z = f2bf_rne(a2 * invd); pa.w = f2bf_rne(a3 * invd);
    pb.x = f2bf_rne(a4 * invd); pb.y = f2bf_rne(a5 * invd);
    pb.z = f2bf_rne(a6 * invd); pb.w = f2bf_rne(a7 * invd);
    *(ushort4*)(orow)     = pa;
    *(ushort4*)(orow + 4) = pb;
}

// ===========================================================================
// MFMA node update: out = [meanb || hb] @ bf16([Wl;Wr]) + bl  (fp32 accum)
//   MODE 0: h' = relu(LN(out)) + h_fp32   (+ bf16 shadow outb)
//   MODE 1: h' = l2normalize(out + h_fp32)
// Block = 256 thr = 4 waves; wave = 16 nodes x 64 cols via 16x16x32 MFMA.
// A-fragments read straight from global (row = lane&15, k = quad*8+j);
// W^T staged once in LDS bf16 (b-frag rows = col's k-values).
// C/D layout: col = lane&15, row = quad*4 + reg.
// ===========================================================================
template <int MODE>
__global__ __launch_bounds__(256, 4) void node_update(
    const float* __restrict__ h,             // [N,64] fp32 residual source
    const unsigned short* __restrict__ meanb,// [N,64] bf16 neighbor mean
    const unsigned short* __restrict__ hb,   // [N,64] bf16 self features
    const float* __restrict__ Wl,            // [64,64] fp32 row-major
    const float* __restrict__ bl,            // [64]
    const float* __restrict__ Wr,            // [64,64]
    const float* __restrict__ g,             // [64] LN gamma (MODE 0)
    const float* __restrict__ b,             // [64] LN beta  (MODE 0)
    float* __restrict__ out,                 // [N,64]
    unsigned short* __restrict__ outb,       // [N,64] bf16 shadow (MODE 0)
    int nNodes) {
    __shared__ unsigned short sWt[64 * WSTR];  // W^T: [col c][k], k<64 Wl, k>=64 Wr
    __shared__ float sbl[DD], sg[DD], sb[DD];

    const int t = threadIdx.x;

    // Stage W^T as bf16 (coalesced global reads; scattered one-time LDS writes).
    for (int idx = t; idx < 2 * DD * DD; idx += 256) {
        int k = idx >> 6, c = idx & 63;
        float v = (k < DD) ? Wl[idx] : Wr[idx - DD * DD];
        sWt[c * WSTR + k] = f2bf_rne(v);
    }
    if (t < DD) {
        sbl[t] = bl[t];
        if (MODE == 0) { sg[t] = g[t]; sb[t] = b[t]; }
    }
    __syncthreads();

    const int wave = t >> 6;
    const int lane = t & 63;
    const int quad = lane >> 4;
    const int n16  = lane & 15;
    const int nbase = blockIdx.x * 64 + wave * 16;

    // A-fragments: row = nbase + n16, k-chunk = quad*8 (+32 per k-step).
    const int arow = min(nbase + n16, nNodes - 1);
    const unsigned short* mrow = meanb + (size_t)arow * DD;
    const unsigned short* hrow = hb    + (size_t)arow * DD;
    short8 af[4];
    af[0] = *(const short8*)(mrow + quad * 8);
    af[1] = *(const short8*)(mrow + 32 + quad * 8);
    af[2] = *(const short8*)(hrow + quad * 8);
    af[3] = *(const short8*)(hrow + 32 + quad * 8);

    // Residual (fp32): rows quad*4+i, cols j*16+n16.
    const int rbase = nbase + quad * 4;
    float res[4][4];
#pragma unroll
    for (int i = 0; i < 4; ++i) {
        int rr = min(rbase + i, nNodes - 1);
#pragma unroll
        for (int j = 0; j < 4; ++j)
            res[i][j] = h[(size_t)rr * DD + j * 16 + n16];
    }

    // Accumulators, bias-initialized (bias depends only on col).
    f32x4 acc[4];
#pragma unroll
    for (int j = 0; j < 4; ++j) {
        float bv = sbl[j * 16 + n16];
        acc[j] = (f32x4){bv, bv, bv, bv};
    }

    // K-loop: 4 steps of K=32, 4 col-tiles each.
#pragma unroll
    for (int s = 0; s < 4; ++s) {
#pragma unroll
        for (int j = 0; j < 4; ++j) {
            short8 bf = *(const short8*)(&sWt[(j * 16 + n16) * WSTR + s * 32 + quad * 8]);
            acc[j] = __builtin_amdgcn_mfma_f32_16x16x32_bf16(af[s], bf, acc[j], 0, 0, 0);
        }
    }

    // Epilogue per row i (row data lives in the quad's 16 lanes x 4 col-tiles).
#pragma unroll
    for (int i = 0; i < 4; ++i) {
        int rr = rbase + i;
        float o[4];
        if (MODE == 0) {
            float s4 = acc[0][i] + acc[1][i] + acc[2][i] + acc[3][i];
            s4 += __shfl_xor(s4, 1, 64);
            s4 += __shfl_xor(s4, 2, 64);
            s4 += __shfl_xor(s4, 4, 64);
            s4 += __shfl_xor(s4, 8, 64);
            float mu = s4 * (1.0f / 64.0f);
            float d0 = acc[0][i] - mu, d1 = acc[1][i] - mu,
                  d2 = acc[2][i] - mu, d3 = acc[3][i] - mu;
            float qq = d0 * d0 + d1 * d1 + d2 * d2 + d3 * d3;
            qq += __shfl_xor(qq, 1, 64);
            qq += __shfl_xor(qq, 2, 64);
            qq += __shfl_xor(qq, 4, 64);
            qq += __shfl_xor(qq, 8, 64);
            float rstd = rsqrtf(qq * (1.0f / 64.0f) + 1e-5f);
            o[0] = fmaxf(d0 * rstd * sg[0 * 16 + n16] + sb[0 * 16 + n16], 0.f) + res[i][0];
            o[1] = fmaxf(d1 * rstd * sg[1 * 16 + n16] + sb[1 * 16 + n16], 0.f) + res[i][1];
            o[2] = fmaxf(d2 * rstd * sg[2 * 16 + n16] + sb[2 * 16 + n16], 0.f) + res[i][2];
            o[3] = fmaxf(d3 * rstd * sg[3 * 16 + n16] + sb[3 * 16 + n16], 0.f) + res[i][3];
        } else {
            o[0] = acc[0][i] + res[i][0];
            o[1] = acc[1][i] + res[i][1];
            o[2] = acc[2][i] + res[i][2];
            o[3] = acc[3][i] + res[i][3];
            float qq = o[0] * o[0] + o[1] * o[1] + o[2] * o[2] + o[3] * o[3];
            qq += __shfl_xor(qq, 1, 64);
            qq += __shfl_xor(qq, 2, 64);
            qq += __shfl_xor(qq, 4, 64);
            qq += __shfl_xor(qq, 8, 64);
            float inv = 1.0f / fmaxf(sqrtf(qq), 1e-12f);
            o[0] *= inv; o[1] *= inv; o[2] *= inv; o[3] *= inv;
        }
        if (rr < nNodes) {
#pragma unroll
            for (int j = 0; j < 4; ++j) {
                out[(size_t)rr * DD + j * 16 + n16] = o[j];
                if (MODE == 0)
                    outb[(size_t)rr * DD + j * 16 + n16] = f2bf_rne(o[j]);
            }
        }
    }
}

// ===========================================================================
extern "C" void kernel_launch(void* const* d_in, const int* in_sizes, int n_in,
                              void* d_out, int out_size, void* d_ws, size_t ws_size,
                              hipStream_t stream) {
    const float* x   = (const float*)d_in[0];
    const int*   ei  = (const int*)d_in[1];   // [2, E] int32: row0 = src, row1 = dst
    const float* Wl0 = (const float*)d_in[2];
    const float* bl0 = (const float*)d_in[3];
    const float* Wr0 = (const float*)d_in[4];
    const float* Wl1 = (const float*)d_in[5];
    const float* bl1 = (const float*)d_in[6];
    const float* Wr1 = (const float*)d_in[7];
    const float* Wl2 = (const float*)d_in[8];
    const float* bl2 = (const float*)d_in[9];
    const float* Wr2 = (const float*)d_in[10];
    const float* g0  = (const float*)d_in[11];
    const float* b0  = (const float*)d_in[12];
    const float* g1  = (const float*)d_in[13];
    const float* b1  = (const float*)d_in[14];

    const int N = in_sizes[0] / DD;   // 100000
    const int E = in_sizes[1] / 2;    // 1250000
    const int* src = ei;
    const int* dst = ei + E;
    const int NB = (N + BNODES - 1) >> BSH;   // 196 buckets

    // Workspace: A | B (f32 N*64) | AGGB | HB (bf16 N*64) | offsets[N+1] |
    //            gCnt[256] | csrBase[256] | csr[E]
    // bucketBuf int2[NB<<13] aliases A (dead before nu0 writes A).
    float* A       = (float*)d_ws;
    float* B       = A + (size_t)N * DD;
    unsigned short* AGGB = (unsigned short*)(B + (size_t)N * DD);
    unsigned short* HB   = AGGB + (size_t)N * DD;
    int*   offsets = (int*)(HB + (size_t)N * DD);
    int*   gCnt    = offsets + (N + 1);
    int*   csrBase = gCnt + 256;
    int*   csr     = csrBase + 256;
    int2*  bucketBuf = (int2*)A;
    float* out     = (float*)d_out;

    const int tiles = (N + 63) / 64;
    const int agrid = (N + 31) / 32;          // 32 nodes/block (8-lane groups)
    const int n4    = N * DD / 4;             // float4 count for cvt
    const int cgrid = (n4 + 255) / 256;
    const int bgrid = (E + 4095) / 4096;

    // ---- CSR build: bucket counting sort (graph static across layers)
    cvt_kernel<<<cgrid, 256, 0, stream>>>(x, HB, n4, gCnt);   // HB=bf16(x), gCnt=0
    bucket_kernel<<<bgrid, 1024, 0, stream>>>(src, dst, gCnt, bucketBuf, E);
    scan_buckets<<<1, 256, 0, stream>>>(gCnt, csrBase, NB);
    csr_build<<<NB, 512, 0, stream>>>(bucketBuf, gCnt, csrBase, offsets, csr, N, E);

    // ---- layer 0 (x -> A); HB becomes bf16(A)
    aggregate_kernel<<<agrid, 256, 0, stream>>>(HB, offsets, csr, AGGB, N);
    node_update<0><<<tiles, 256, 0, stream>>>(x, AGGB, HB, Wl0, bl0, Wr0, g0, b0, A, HB, N);

    // ---- layer 1 (A -> B); HB becomes bf16(B)
    aggregate_kernel<<<agrid, 256, 0, stream>>>(HB, offsets, csr, AGGB, N);
    node_update<0><<<tiles, 256, 0, stream>>>(A, AGGB, HB, Wl1, bl1, Wr1, g1, b1, B, HB, N);

    // ---- layer 2 (B -> out)
    aggregate_kernel<<<agrid, 256, 0, stream>>>(HB, offsets, csr, AGGB, N);
    node_update<1><<<tiles, 256, 0, stream>>>(B, AGGB, HB, Wl2, bl2, Wr2, nullptr, nullptr, out, nullptr, N);
}

// Round 9
// 314.121 us; speedup vs baseline: 1.4536x; 1.0003x over previous
//
#include <hip/hip_runtime.h>

#define DD   64      // channels
#define WSTR 136     // LDS W^T row stride (bf16 elems): 2-way conflicts only (free)
#define SSTR 72      // LDS self/mean tile row stride (bf16 elems): 2-way only
#define BSH  9       // 512 nodes per bucket
#define BNODES 512
#define BCAPSH 13    // 8192 edges capacity per bucket (mean 6400 + 22 sigma)

typedef unsigned int uint32;
typedef __attribute__((ext_vector_type(8))) short short8;   // 8 bf16 (4 VGPRs)
typedef __attribute__((ext_vector_type(4))) float f32x4;    // MFMA accumulator

__device__ __forceinline__ unsigned short f2bf_rne(float f) {
    uint32 u = __float_as_uint(f);
    u += 0x7fffu + ((u >> 16) & 1u);   // round-to-nearest-even
    return (unsigned short)(u >> 16);
}
__device__ __forceinline__ float bf_lo(uint32 w) { return __uint_as_float(w << 16); }
__device__ __forceinline__ float bf_hi(uint32 w) { return __uint_as_float(w & 0xffff0000u); }
__device__ __forceinline__ float bf2f(unsigned short s) {
    return __uint_as_float(((uint32)s) << 16);
}

// ===========================================================================
// x (fp32) -> bf16 shadow; block 0 also zeroes the bucket counters.
// ===========================================================================
__global__ __launch_bounds__(256) void cvt_kernel(const float* __restrict__ x,
                                                  unsigned short* __restrict__ xb,
                                                  int n4, int* __restrict__ gCnt) {
    if (blockIdx.x == 0 && threadIdx.x < 256) gCnt[threadIdx.x] = 0;
    int i = blockIdx.x * 256 + threadIdx.x;
    if (i < n4) {
        float4 v = ((const float4*)x)[i];
        ushort4 p;
        p.x = f2bf_rne(v.x); p.y = f2bf_rne(v.y);
        p.z = f2bf_rne(v.z); p.w = f2bf_rne(v.w);
        ((ushort4*)xb)[i] = p;
    }
}

// ===========================================================================
// Pass 1: bucket edges by dst>>9 (LDS histogram, one global atomic per
// (block,bucket), scatter (src,dst) into fixed-capacity bucket regions).
// ===========================================================================
__global__ __launch_bounds__(1024) void bucket_kernel(const int* __restrict__ src,
                                                      const int* __restrict__ dst,
                                                      int* __restrict__ gCnt,
                                                      int2* __restrict__ buf, int E) {
    __shared__ int ldsCnt[256];
    __shared__ int base[256];
    const int t = threadIdx.x;
    if (t < 256) ldsCnt[t] = 0;
    __syncthreads();

    const int e0 = blockIdx.x * 4096;
    int bk[4], rk[4], sv[4], dv[4];
#pragma unroll
    for (int k = 0; k < 4; ++k) {
        int e = e0 + k * 1024 + t;
        bk[k] = -1;
        if (e < E) {
            dv[k] = dst[e];
            sv[k] = src[e];
            bk[k] = dv[k] >> BSH;
            rk[k] = atomicAdd(&ldsCnt[bk[k]], 1);
        }
    }
    __syncthreads();
    if (t < 256 && ldsCnt[t] > 0) base[t] = atomicAdd(&gCnt[t], ldsCnt[t]);
    __syncthreads();
#pragma unroll
    for (int k = 0; k < 4; ++k) {
        if (bk[k] >= 0) {
            int pos = (bk[k] << BCAPSH) + base[bk[k]] + rk[k];
            buf[pos] = make_int2(sv[k], dv[k]);
        }
    }
}

// ===========================================================================
// Pass 2: one block per bucket. Internal scan of gCnt gives the bucket base
// (scan_buckets dispatch folded in). LDS count -> LDS scan -> offsets ->
// scatter src into this bucket's csr window (single-CU stores, no bounce).
// ===========================================================================
__global__ __launch_bounds__(512) void csr_build(const int2* __restrict__ buf,
                                                 const int* __restrict__ gCnt,
                                                 int* __restrict__ offsets,
                                                 int* __restrict__ csr, int N, int E) {
    __shared__ int c1[BNODES];
    __shared__ int s[BNODES];
    __shared__ int sg2[256];
    const int b = blockIdx.x;
    const int t = threadIdx.x;
    if (t < 256) sg2[t] = gCnt[t];
    c1[t] = 0;
    __syncthreads();
    // inclusive scan of bucket counts (256 entries)
    for (int d = 1; d < 256; d <<= 1) {
        int v = (t < 256 && t >= d) ? sg2[t - d] : 0;
        __syncthreads();
        if (t < 256 && t >= d) sg2[t] += v;
        __syncthreads();
    }
    const int base = (b == 0) ? 0 : sg2[b - 1];
    const int cnt = gCnt[b];
    const int2* bb = buf + ((size_t)b << BCAPSH);
    for (int i = t; i < cnt; i += 512) atomicAdd(&c1[bb[i].y & (BNODES - 1)], 1);
    __syncthreads();

    int v = c1[t];
    s[t] = v;
    __syncthreads();
    for (int d = 1; d < BNODES; d <<= 1) {
        int u = (t >= d) ? s[t - d] : 0;
        __syncthreads();
        if (t >= d) s[t] += u;
        __syncthreads();
    }
    int excl = s[t] - v;
    const int node = (b << BSH) + t;
    if (node < N) offsets[node] = base + excl;
    if (b == 0 && t == 0) offsets[N] = E;
    __syncthreads();
    s[t] = excl;
    c1[t] = 0;
    __syncthreads();

    for (int i = t; i < cnt; i += 512) {
        int2 e = bb[i];
        int d = e.y & (BNODES - 1);
        int r = atomicAdd(&c1[d], 1);
        csr[base + s[d] + r] = e.x;
    }
}

// ===========================================================================
// Fused SAGE layer (all-bf16 inter-layer state):
//   phase 1: stage W^T (bf16 LDS), self tile (LDS), gather neighbor means
//            (8 lanes/node, 8-deep batches) -> LDS mean tile
//   phase 2: MFMA 16x16x32 [mean||self] @ [Wl;Wr] + bl, fp32 accum;
//            MODE 0: hbout = bf16(relu(LN(y)) + self)
//            MODE 1: out   = l2normalize(y + self)  (fp32)
// Block = 256 thr = 4 waves = 64 dst nodes. C/D: col=lane&15, row=quad*4+reg.
// ===========================================================================
template <int MODE>
__global__ __launch_bounds__(256, 4) void sage_layer(
    const unsigned short* __restrict__ hbin,  // [N,64] bf16 layer input
    const int* __restrict__ offsets,          // [N+1]
    const int* __restrict__ csr,              // [E]
    const float* __restrict__ Wl,             // [64,64] fp32 row-major
    const float* __restrict__ bl,             // [64]
    const float* __restrict__ Wr,             // [64,64]
    const float* __restrict__ g,              // [64] LN gamma (MODE 0)
    const float* __restrict__ bta,            // [64] LN beta  (MODE 0)
    unsigned short* __restrict__ hbout,       // [N,64] bf16 (MODE 0)
    float* __restrict__ out,                  // [N,64] fp32 (MODE 1)
    int N) {
    __shared__ unsigned short sWt[64 * WSTR];   // W^T: [col][k] k<64 Wl, k>=64 Wr
    __shared__ unsigned short sSelf[64 * SSTR]; // self rows bf16
    __shared__ unsigned short sMean[64 * SSTR]; // gathered means bf16
    __shared__ float sbl[DD], sg[DD], sb[DD];

    const int t = threadIdx.x;
    const int nbase = blockIdx.x * 64;

    // ---- stage W^T as bf16
    for (int idx = t; idx < 2 * DD * DD; idx += 256) {
        int k = idx >> 6, c = idx & 63;
        float v = (k < DD) ? Wl[idx] : Wr[idx - DD * DD];
        sWt[c * WSTR + k] = f2bf_rne(v);
    }
    if (t < DD) {
        sbl[t] = bl[t];
        if (MODE == 0) { sg[t] = g[t]; sb[t] = bta[t]; }
    }

    // ---- stage self tile: 64 rows x 8 uint4 chunks, coalesced
#pragma unroll
    for (int r = 0; r < 2; ++r) {
        int idx = r * 256 + t;
        int row = idx >> 3;
        int qq  = idx & 7;
        int n   = min(nbase + row, N - 1);
        uint4 v = ((const uint4*)(hbin + (size_t)n * DD))[qq];
        *(uint4*)(&sSelf[row * SSTR + qq * 8]) = v;
    }

    // ---- gather neighbor means: 32 groups x 8 lanes; 2 nodes per group
    {
        const int grp = t >> 3;
        const int q   = t & 7;           // 16 B chunk within 128 B row
#pragma unroll 1
        for (int rep = 0; rep < 2; ++rep) {
            int local = grp + rep * 32;
            int node  = nbase + local;
            float a0 = 0.f, a1 = 0.f, a2 = 0.f, a3 = 0.f,
                  a4 = 0.f, a5 = 0.f, a6 = 0.f, a7 = 0.f;
            int deg = 0;
            if (node < N) {
                int off0 = offsets[node];
                int off1 = offsets[node + 1];
                deg = off1 - off0;
                for (int j = off0; j < off1; j += 8) {
                    uint4 v[8];
#pragma unroll
                    for (int s = 0; s < 8; ++s) {
                        uint4 tt = make_uint4(0u, 0u, 0u, 0u);
                        int idx = j + s;
                        if (idx < off1) {
                            int sn = __builtin_nontemporal_load(&csr[idx]);
                            tt = ((const uint4*)(hbin + (size_t)sn * DD))[q];
                        }
                        v[s] = tt;
                    }
#pragma unroll
                    for (int s = 0; s < 8; ++s) {
                        a0 += bf_lo(v[s].x); a1 += bf_hi(v[s].x);
                        a2 += bf_lo(v[s].y); a3 += bf_hi(v[s].y);
                        a4 += bf_lo(v[s].z); a5 += bf_hi(v[s].z);
                        a6 += bf_lo(v[s].w); a7 += bf_hi(v[s].w);
                    }
                }
            }
            float invd = 1.0f / fmaxf((float)deg, 1.0f);
            ushort4 pa, pb;
            pa.x = f2bf_rne(a0 * invd); pa.y = f2bf_rne(a1 * invd);
            pa.z = f2bf_rne(a2 * invd); pa.w = f2bf_rne(a3 * invd);
            pb.x = f2bf_rne(a4 * invd); pb.y = f2bf_rne(a5 * invd);
            pb.z = f2bf_rne(a6 * invd); pb.w = f2bf_rne(a7 * invd);
            *(ushort4*)(&sMean[local * SSTR + q * 8])     = pa;
            *(ushort4*)(&sMean[local * SSTR + q * 8 + 4]) = pb;
        }
    }
    __syncthreads();

    // ---- MFMA phase: wave = 16 nodes x 64 cols
    const int wave = t >> 6;
    const int lane = t & 63;
    const int quad = lane >> 4;
    const int n16  = lane & 15;
    const int lbase = wave * 16;

    short8 af[4];
    af[0] = *(const short8*)(&sMean[(lbase + n16) * SSTR + quad * 8]);
    af[1] = *(const short8*)(&sMean[(lbase + n16) * SSTR + 32 + quad * 8]);
    af[2] = *(const short8*)(&sSelf[(lbase + n16) * SSTR + quad * 8]);
    af[3] = *(const short8*)(&sSelf[(lbase + n16) * SSTR + 32 + quad * 8]);

    f32x4 acc[4];
#pragma unroll
    for (int j = 0; j < 4; ++j) {
        float bv = sbl[j * 16 + n16];
        acc[j] = (f32x4){bv, bv, bv, bv};
    }
#pragma unroll
    for (int s = 0; s < 4; ++s) {
#pragma unroll
        for (int j = 0; j < 4; ++j) {
            short8 bf = *(const short8*)(&sWt[(j * 16 + n16) * WSTR + s * 32 + quad * 8]);
            acc[j] = __builtin_amdgcn_mfma_f32_16x16x32_bf16(af[s], bf, acc[j], 0, 0, 0);
        }
    }

    // ---- epilogue; residual from the LDS self tile (bf16)
#pragma unroll
    for (int i = 0; i < 4; ++i) {
        const int lrow = lbase + quad * 4 + i;
        const int rr   = nbase + lrow;
        float res[4];
#pragma unroll
        for (int j = 0; j < 4; ++j)
            res[j] = bf2f(sSelf[lrow * SSTR + j * 16 + n16]);
        float o[4];
        if (MODE == 0) {
            float s4 = acc[0][i] + acc[1][i] + acc[2][i] + acc[3][i];
            s4 += __shfl_xor(s4, 1, 64);
            s4 += __shfl_xor(s4, 2, 64);
            s4 += __shfl_xor(s4, 4, 64);
            s4 += __shfl_xor(s4, 8, 64);
            float mu = s4 * (1.0f / 64.0f);
            float d0 = acc[0][i] - mu, d1 = acc[1][i] - mu,
                  d2 = acc[2][i] - mu, d3 = acc[3][i] - mu;
            float qq = d0 * d0 + d1 * d1 + d2 * d2 + d3 * d3;
            qq += __shfl_xor(qq, 1, 64);
            qq += __shfl_xor(qq, 2, 64);
            qq += __shfl_xor(qq, 4, 64);
            qq += __shfl_xor(qq, 8, 64);
            float rstd = rsqrtf(qq * (1.0f / 64.0f) + 1e-5f);
            o[0] = fmaxf(d0 * rstd * sg[ 0 + n16] + sb[ 0 + n16], 0.f) + res[0];
            o[1] = fmaxf(d1 * rstd * sg[16 + n16] + sb[16 + n16], 0.f) + res[1];
            o[2] = fmaxf(d2 * rstd * sg[32 + n16] + sb[32 + n16], 0.f) + res[2];
            o[3] = fmaxf(d3 * rstd * sg[48 + n16] + sb[48 + n16], 0.f) + res[3];
        } else {
            o[0] = acc[0][i] + res[0];
            o[1] = acc[1][i] + res[1];
            o[2] = acc[2][i] + res[2];
            o[3] = acc[3][i] + res[3];
            float qq = o[0] * o[0] + o[1] * o[1] + o[2] * o[2] + o[3] * o[3];
            qq += __shfl_xor(qq, 1, 64);
            qq += __shfl_xor(qq, 2, 64);
            qq += __shfl_xor(qq, 4, 64);
            qq += __shfl_xor(qq, 8, 64);
            float inv = 1.0f / fmaxf(sqrtf(qq), 1e-12f);
            o[0] *= inv; o[1] *= inv; o[2] *= inv; o[3] *= inv;
        }
        if (rr < N) {
#pragma unroll
            for (int j = 0; j < 4; ++j) {
                if (MODE == 0)
                    hbout[(size_t)rr * DD + j * 16 + n16] = f2bf_rne(o[j]);
                else
                    out[(size_t)rr * DD + j * 16 + n16] = o[j];
            }
        }
    }
}

// ===========================================================================
extern "C" void kernel_launch(void* const* d_in, const int* in_sizes, int n_in,
                              void* d_out, int out_size, void* d_ws, size_t ws_size,
                              hipStream_t stream) {
    const float* x   = (const float*)d_in[0];
    const int*   ei  = (const int*)d_in[1];   // [2, E] int32: row0 = src, row1 = dst
    const float* Wl0 = (const float*)d_in[2];
    const float* bl0 = (const float*)d_in[3];
    const float* Wr0 = (const float*)d_in[4];
    const float* Wl1 = (const float*)d_in[5];
    const float* bl1 = (const float*)d_in[6];
    const float* Wr1 = (const float*)d_in[7];
    const float* Wl2 = (const float*)d_in[8];
    const float* bl2 = (const float*)d_in[9];
    const float* Wr2 = (const float*)d_in[10];
    const float* g0  = (const float*)d_in[11];
    const float* b0  = (const float*)d_in[12];
    const float* g1  = (const float*)d_in[13];
    const float* b1  = (const float*)d_in[14];

    const int N = in_sizes[0] / DD;   // 100000
    const int E = in_sizes[1] / 2;    // 1250000
    const int* src = ei;
    const int* dst = ei + E;
    const int NB = (N + BNODES - 1) >> BSH;   // 196 buckets

    // Workspace: bucketBuf int2[256<<13] | HB0, HB1 bf16[N*64] | csr[E] |
    //            offsets[N+1] | gCnt[256]   (~48 MB)
    int2* bucketBuf = (int2*)d_ws;
    unsigned short* HB0 = (unsigned short*)(bucketBuf + ((size_t)256 << BCAPSH));
    unsigned short* HB1 = HB0 + (size_t)N * DD;
    int*   csr     = (int*)(HB1 + (size_t)N * DD);
    int*   offsets = csr + E;
    int*   gCnt    = offsets + (N + 1);
    float* out     = (float*)d_out;

    const int tiles = (N + 63) / 64;
    const int n4    = N * DD / 4;
    const int cgrid = (n4 + 255) / 256;
    const int bgrid = (E + 4095) / 4096;

    // ---- CSR build: bucket counting sort (graph static across layers)
    cvt_kernel<<<cgrid, 256, 0, stream>>>(x, HB0, n4, gCnt);   // HB0=bf16(x), gCnt=0
    bucket_kernel<<<bgrid, 1024, 0, stream>>>(src, dst, gCnt, bucketBuf, E);
    csr_build<<<NB, 512, 0, stream>>>(bucketBuf, gCnt, offsets, csr, N, E);

    // ---- 3 fused layers (bf16 ping-pong)
    sage_layer<0><<<tiles, 256, 0, stream>>>(HB0, offsets, csr, Wl0, bl0, Wr0,
                                             g0, b0, HB1, nullptr, N);
    sage_layer<0><<<tiles, 256, 0, stream>>>(HB1, offsets, csr, Wl1, bl1, Wr1,
                                             g1, b1, HB0, nullptr, N);
    sage_layer<1><<<tiles, 256, 0, stream>>>(HB0, offsets, csr, Wl2, bl2, Wr2,
                                             nullptr, nullptr, nullptr, out, N);
}